// Round 15
// baseline (600.933 us; speedup 1.0000x reference)
//
#include <hip/hip_runtime.h>
#include <cstddef>

#define NSEQ 20480
#define EPSf 1e-7f
#define MAXN 0.99999f
#define MAXN2 (0.99999f * 0.99999f)
#define QCLIP (1.f - MAXN2)        // 1 - ||z||^2 at the projection boundary
#define GS_CLIP 6.1030949f         // atanh(MAXN)/MAXN

typedef __attribute__((ext_vector_type(8))) short bf16x8;
typedef __attribute__((ext_vector_type(4))) float f32x4;

__device__ __forceinline__ unsigned short f2bf(float x) {
  unsigned u = __float_as_uint(x);
  u += 0x7FFF + ((u >> 16) & 1);
  return (unsigned short)(u >> 16);
}
__device__ __forceinline__ float bf2f(unsigned short h) {
  return __uint_as_float(((unsigned)h) << 16);
}
// async global->LDS, 16B/lane; dst wave-uniform base (HW adds lane*16), src per-lane
__device__ __forceinline__ void gload16(const void* g, void* l) {
  __builtin_amdgcn_global_load_lds(
      (const __attribute__((address_space(1))) void*)g,
      (__attribute__((address_space(3))) void*)l, 16, 0, 0);
}
// hardware-transcendental fast math (v_exp_f32 / v_log_f32 / v_rcp_f32)
__device__ __forceinline__ float fast_exp(float a) {          // e^a
  return exp2f(a * 1.44269504f);
}
__device__ __forceinline__ float fast_tanh(float a) {         // exact formula, HW exp
  float e = fast_exp(2.f * a);
  return 1.f - 2.f * __builtin_amdgcn_rcpf(e + 1.f);
}
__device__ __forceinline__ float fast_atanh(float x) {        // x in [0, 1-1e-6]
  return 0.34657359f * log2f((1.f + x) * __builtin_amdgcn_rcpf(1.f - x));
}
__device__ __forceinline__ float sech2f(float a) {            // 1 - tanh^2(a), a >= 0
  float u = fast_exp(-2.f * a);
  float om = 1.f + u;
  return 4.f * u * __builtin_amdgcn_rcpf(om * om);
}

// Activation tiled layout (same as weights): act[kg][m][e], kg=k>>3, e=k&7
// addr = (kg*NSEQ + m)*8 + e

// ---------------- fold transpose: X[b][l][f] (4 arrays) -> XT[ch][b*64+f][l], ch0 = sum ----------------
__global__ __launch_bounds__(256) void fold_transpose(
    const float* __restrict__ t, const float* __restrict__ c,
    const float* __restrict__ f, const float* __restrict__ r,
    float* __restrict__ XT)
{
  __shared__ float tile[4][56][65];
  const int b = blockIdx.x, l0 = blockIdx.y * 56;
  const int tid = threadIdx.x;
  const int fi = tid & 63, lr0 = tid >> 6;
#pragma unroll
  for (int i = 0; i < 14; ++i) {
    int lr = lr0 + i * 4;
    size_t idx = ((size_t)b * 336 + l0 + lr) * 64 + fi;
    tile[0][lr][fi] = t[idx];
    tile[1][lr][fi] = c[idx];
    tile[2][lr][fi] = f[idx];
    tile[3][lr][fi] = r[idx];
  }
  __syncthreads();
#pragma unroll
  for (int ch = 0; ch < 5; ++ch) {
    for (int i = 0; i < 14; ++i) {
      int idx2 = i * 256 + tid;
      int ff = idx2 / 56, ll = idx2 % 56;
      float v;
      if (ch == 0) v = tile[0][ll][ff] + tile[1][ll][ff] + tile[2][ll][ff] + tile[3][ll][ff];
      else v = tile[ch - 1][ll][ff];
      XT[((size_t)ch * 4096 + (b << 6) + ff) * 336 + l0 + ll] = v;
    }
  }
}

// ---------------- weight split+tile: W[k][n] f32 -> Wh(/Wl) bf16 at [(k>>3)*N + n]*8 + (k&7) ----------------
__global__ __launch_bounds__(256) void conv_weight(
    const float* __restrict__ W, unsigned short* __restrict__ Wh, unsigned short* __restrict__ Wl,
    int K, int N, int Nsrc)
{
  int idx = blockIdx.x * 256 + threadIdx.x;
  if (idx >= K * N) return;
  int k = idx / N, n = idx % N;
  float x = (n < Nsrc) ? W[(size_t)k * Nsrc + n] : 0.f;
  unsigned short h = f2bf(x);
  size_t o = ((size_t)(k >> 3) * N + n) * 8 + (k & 7);
  Wh[o] = h;
  if (Wl) Wl[o] = f2bf(x - bf2f(h));
}

// ---------------- W_emb -> MFMA B-fragment layout: Wg[T][lane][j], k=8*(lane>>4)+j, n=T*16+(lane&15) ----------------
__global__ __launch_bounds__(256) void conv_wemb(
    const float* __restrict__ W_emb, unsigned short* __restrict__ WgH, unsigned short* __restrict__ WgL)
{
  int idx = blockIdx.x * 256 + threadIdx.x;
  if (idx >= 16 * 64 * 8) return;
  int j = idx & 7, ln = (idx >> 3) & 63, T = idx >> 9;
  int k = 8 * (ln >> 4) + j, n = T * 16 + (ln & 15);
  float x = (k < 24) ? W_emb[(size_t)k * 256 + n] : 0.f;
  unsigned short h = f2bf(x);
  WgH[idx] = h;
  WgL[idx] = f2bf(x - bf2f(h));
}

// ---------------- init: MFMA embed + expmap0 + parallel velocity pairs, one WAVE per sequence ----------------
// Zero-LDS, zero-barrier: A-frags direct from XT, B-frags direct from L2-resident WgH/WgL
__global__ __launch_bounds__(256) void init_kernel(
    const float* __restrict__ XT,
    const unsigned short* __restrict__ WgH, const unsigned short* __restrict__ WgL,
    const float* __restrict__ b_emb,
    unsigned short* __restrict__ Uh, unsigned short* __restrict__ Ul,
    float* __restrict__ ZL, float* __restrict__ QN, unsigned short* __restrict__ VO)
{
  const int tid = threadIdx.x, w = tid >> 6, lane = tid & 63;
  const int l15 = lane & 15, l4 = lane >> 4;
  const int sidx = blockIdx.x * 4 + w;

  // A fragment: A[row=l15][k=8*l4+j] = XT[sidx*336 + l15*24 + l4*8 + j]; l4==3 -> 0
  bf16x8 ah, al;
  if (l4 < 3) {
    const float* sp = XT + (size_t)sidx * 336 + l15 * 24 + l4 * 8;  // 16B aligned
    float4 q0 = *(const float4*)sp;
    float4 q1 = *(const float4*)(sp + 4);
    float vv[8] = {q0.x, q0.y, q0.z, q0.w, q1.x, q1.y, q1.z, q1.w};
#pragma unroll
    for (int j = 0; j < 8; ++j) {
      unsigned short h = f2bf(vv[j]);
      ah[j] = (short)h;
      al[j] = (short)f2bf(vv[j] - bf2f(h));
    }
  } else {
#pragma unroll
    for (int j = 0; j < 8; ++j) { ah[j] = 0; al[j] = 0; }
  }

  // 16 N-tiles x 3 split MFMAs, B-frags straight from global (32 KB, L2-resident)
  const bf16x8* BH = (const bf16x8*)WgH;   // index T*64 + lane
  const bf16x8* BL = (const bf16x8*)WgL;
  f32x4 acc[16];
#pragma unroll
  for (int T = 0; T < 16; ++T) acc[T] = (f32x4){0.f, 0.f, 0.f, 0.f};
#pragma unroll
  for (int T = 0; T < 16; ++T) {
    bf16x8 bh = BH[T * 64 + lane];
    bf16x8 bl = BL[T * 64 + lane];
    acc[T] = __builtin_amdgcn_mfma_f32_16x16x32_bf16(ah, bh, acc[T], 0, 0, 0);
    acc[T] = __builtin_amdgcn_mfma_f32_16x16x32_bf16(ah, bl, acc[T], 0, 0, 0);
    acc[T] = __builtin_amdgcn_mfma_f32_16x16x32_bf16(al, bh, acc[T], 0, 0, 0);
  }

  float z_[4][16];
  float q_[4];      // 1 - ||z_s||^2, cancellation-free
  float tn_[4];     // ||z_s|| post-projection
  float vn_[4];     // pre-tanh norm (atanh identity)
  float ls[4] = {0.f, 0.f, 0.f, 0.f};
#pragma unroll
  for (int T = 0; T < 16; ++T) {
    float b = b_emb[T * 16 + l15];
#pragma unroll
    for (int r = 0; r < 4; ++r) {
      float e = fast_tanh(acc[T][r] + b);
      z_[r][T] = e;
      ls[r] = fmaf(e, e, ls[r]);
    }
  }
#pragma unroll
  for (int m = 1; m < 16; m <<= 1)
#pragma unroll
    for (int r = 0; r < 4; ++r) ls[r] += __shfl_xor(ls[r], m);
#pragma unroll
  for (int r = 0; r < 4; ++r) {
    float vn = sqrtf(fmaxf(ls[r], 1e-14f));
    float tt = fast_tanh(vn);           // ||expmap0 pre|| == tanh(||e||) exactly
    bool clip = tt > MAXN;
    float scale = (clip ? MAXN : tt) / vn;
#pragma unroll
    for (int T = 0; T < 16; ++T) z_[r][T] *= scale;
    tn_[r] = clip ? MAXN : tt;
    vn_[r] = vn;
    q_[r] = clip ? QCLIP : sech2f(vn);  // 1 - tanh^2(vn), no cancellation
  }

  // cross-group boundary data: next group's reg0 (z and q)
  float zsh[16], qsh;
#pragma unroll
  for (int T = 0; T < 16; ++T) zsh[T] = __shfl(z_[0][T], (lane + 16) & 63);
  qsh = __shfl(q_[0], (lane + 16) & 63);

  // velocity pairs: group l4 handles t = 4*l4 + p; groups 0-2: 4 pairs, group 3: 1 pair
  float vel[16];
#pragma unroll
  for (int T = 0; T < 16; ++T) vel[T] = 0.f;
  const float p4c = 0.9f * 0.9f * 0.9f * 0.9f;
  const float p8c = p4c * p4c, p12c = p8c * p4c;
  const float wsum = (1.f - p12c * 0.9f) / 0.1f;
  float wt = ((l4 == 0) ? p12c : (l4 == 1) ? p8c : (l4 == 2) ? p4c : 1.f) / wsum;
  const int npairs = (l4 < 3) ? 4 : 1;
#pragma unroll
  for (int p = 0; p < 4; ++p) {
    if (p < npairs) {
      float sd2 = 0.f;                         // ||y - x||^2
#pragma unroll
      for (int T = 0; T < 16; ++T) {
        float zt1 = (p < 3) ? z_[(p + 1) & 3][T] : zsh[T];
        float d = zt1 - z_[p][T];
        sd2 = fmaf(d, d, sd2);
      }
#pragma unroll
      for (int m = 1; m < 16; m <<= 1) sd2 += __shfl_xor(sd2, m);
      float qx = q_[p];
      float qy = (p < 3) ? q_[(p + 1) & 3] : qsh;
      float den = fmaxf(sd2 + qx * qy, 1e-15f);     // 1-2xy+x2y2
      float a2 = (sd2 + qx) / den;                  // (1-2xy+y2)/den
      float b2c = qx / den;                         // (1-x2)/den
      float wd[16];
      float sww = 0.f;
#pragma unroll
      for (int T = 0; T < 16; ++T) {
        float zt1 = (p < 3) ? z_[(p + 1) & 3][T] : zsh[T];
        wd[T] = b2c * zt1 - a2 * z_[p][T];
        sww = fmaf(wd[T], wd[T], sww);
      }
#pragma unroll
      for (int m = 1; m < 16; m <<= 1) sww += __shfl_xor(sww, m);
      float wn = sqrtf(fmaxf(sww, 1e-14f));
      float vls = qx * fast_atanh(fminf(wn, 1.f - 1e-6f)) / wn;   // (2/lam)*atanh/wn
#pragma unroll
      for (int T = 0; T < 16; ++T) {
        float vl = vls * wd[T];
        vel[T] = fmaf(wt, vl, vel[T]);
        if (l4 == 0 && p < 3)
          VO[((size_t)p * NSEQ + sidx) * 256 + T * 16 + l15] = f2bf(vl);
      }
      wt *= (1.f / 0.9f);
    }
  }

#pragma unroll
  for (int T = 0; T < 16; ++T) {
    vel[T] += __shfl_xor(vel[T], 16);
    vel[T] += __shfl_xor(vel[T], 32);
  }

  // outputs in tiled layout: U[kg][m][e]; z13 = group3 reg1
  if (l4 == 3) {
    // atanh(tanh(vn)) == vn: gs = vn/tn (unclipped), const when clipped
    float gs = (tn_[1] >= MAXN) ? GS_CLIP : vn_[1] / tn_[1];
#pragma unroll
    for (int T = 0; T < 16; ++T) {
      int cidx = T * 16 + l15;
      float g = gs * z_[1][T];
      size_t o = ((size_t)(cidx >> 3) * NSEQ + sidx) * 8 + (cidx & 7);
      Uh[o] = f2bf(g);                 // Ul[0:256] never read -> not written
      ZL[(size_t)sidx * 256 + cidx] = z_[1][T];
    }
    if (l15 == 0) QN[sidx] = q_[1];
  }
  if (l4 == 0) {
#pragma unroll
    for (int T = 0; T < 16; ++T) {
      int cidx = 256 + T * 16 + l15;
      unsigned short vh = f2bf(vel[T]);
      size_t o = ((size_t)(cidx >> 3) * NSEQ + sidx) * 8 + (cidx & 7);
      Uh[o] = vh;
      Ul[o] = f2bf(vel[T] - bf2f(vh));
    }
  }
}

// ---------------- single-plane bf16 MFMA GEMM: 128x128 tile, BK=64, global_load_lds staging ----------------
// A: tiled [K/8][NSEQ][8]. B: tiled [K/8][N][8]. K multiple of 64.
// EPI: 1 -> tanh; 2 -> relu (tiled bf16 hi out)
template <int EPI>
__global__ __launch_bounds__(256) void gemm_bf16(
    const unsigned short* __restrict__ Ah, int K,
    const unsigned short* __restrict__ Bh, int N,
    const float* __restrict__ bias,
    unsigned short* __restrict__ Ch)
{
  __shared__ unsigned short As[8][128][8];       // chunk c = kg*128 + m (1024 chunks)
  __shared__ unsigned short Bs[8][128][8];       // chunk c = kg*128 + n
  const int tid = threadIdx.x;
  const int lane = tid & 63, wid = tid >> 6;
  const int wr = wid >> 1, wc = wid & 1;
  const int l15 = lane & 15, l4 = lane >> 4;
  const int row0 = blockIdx.x * 128, col0 = blockIdx.y * 128;
  unsigned short* As_flat = &As[0][0][0];
  unsigned short* Bs_flat = &Bs[0][0][0];

  f32x4 acc[4][4];
#pragma unroll
  for (int i = 0; i < 4; ++i)
#pragma unroll
    for (int j = 0; j < 4; ++j) acc[i][j] = (f32x4){0.f, 0.f, 0.f, 0.f};

  for (int k0 = 0; k0 < K; k0 += 64) {
    const int kb = k0 >> 3;
#pragma unroll
    for (int rd = 0; rd < 4; ++rd) {
      int c = rd * 256 + tid;                    // lanes -> consecutive m, contiguous 1KB/wave
      int kg = c >> 7, m = c & 127;
      gload16(Ah + ((size_t)(kb + kg) * NSEQ + row0 + m) * 8,
              As_flat + (size_t)(rd * 256 + wid * 64) * 8);
    }
#pragma unroll
    for (int rd = 0; rd < 4; ++rd) {
      int c = rd * 256 + tid;
      int kg = c >> 7, n = c & 127;
      gload16(Bh + ((size_t)(kb + kg) * N + col0 + n) * 8,
              Bs_flat + (size_t)(rd * 256 + wid * 64) * 8);
    }
    __syncthreads();

#pragma unroll
    for (int ks = 0; ks < 2; ++ks) {
      bf16x8 fah[4], fbh[4];
#pragma unroll
      for (int mi = 0; mi < 4; ++mi)
        fah[mi] = *(const bf16x8*)&As[ks * 4 + l4][wr * 64 + mi * 16 + l15][0];
#pragma unroll
      for (int ni = 0; ni < 4; ++ni)
        fbh[ni] = *(const bf16x8*)&Bs[ks * 4 + l4][wc * 64 + ni * 16 + l15][0];
#pragma unroll
      for (int mi = 0; mi < 4; ++mi)
#pragma unroll
        for (int ni = 0; ni < 4; ++ni)
          acc[mi][ni] = __builtin_amdgcn_mfma_f32_16x16x32_bf16(fah[mi], fbh[ni], acc[mi][ni], 0, 0, 0);
    }
    __syncthreads();
  }

#pragma unroll
  for (int mi = 0; mi < 4; ++mi)
#pragma unroll
    for (int ni = 0; ni < 4; ++ni) {
      int cc = col0 + wc * 64 + ni * 16 + l15;
      float bv = bias[cc];
      int rbase = row0 + wr * 64 + mi * 16 + l4 * 4;
#pragma unroll
      for (int r = 0; r < 4; ++r) {
        float v = acc[mi][ni][r] + bv;
        if (EPI == 1) v = tanhf(v);
        else v = fmaxf(v, 0.f);
        size_t o = ((size_t)(cc >> 3) * NSEQ + rbase + r) * 8 + (cc & 7);
        Ch[o] = f2bf(v);
      }
    }
}

// ---------------- fused G2+step: V = H @ W2 + b2 (in-register), then hyperbolic step ----------------
// BM=64, BN=256 (full), BK=64; grid NSEQ/64 = 320; 4 waves, wave w owns rows w*16..+16.
// C-layout: lane group l4 owns rows l4*4+r (r=0..3), cols ni*16+l15. Reductions: butterfly over l15.
__global__ __launch_bounds__(256) void gemm2_step(
    const unsigned short* __restrict__ Hh,       // A tiled [64][NSEQ][8], K=512
    const unsigned short* __restrict__ W2h,      // B tiled [64][256][8]
    const float* __restrict__ b2,
    unsigned short* __restrict__ Uh, unsigned short* __restrict__ Ul,
    float* __restrict__ ZL, float* __restrict__ QN,
    const unsigned short* __restrict__ VOk, int k)
{
  __shared__ unsigned short As[8][64][8];        // 8 KB
  __shared__ unsigned short Bs[8][256][8];       // 32 KB
  const int tid = threadIdx.x, lane = tid & 63, wid = tid >> 6;
  const int l15 = lane & 15, l4 = lane >> 4;
  const int row0 = blockIdx.x * 64;
  unsigned short* As_flat = &As[0][0][0];
  unsigned short* Bs_flat = &Bs[0][0][0];

  f32x4 acc[16];
#pragma unroll
  for (int ni = 0; ni < 16; ++ni) acc[ni] = (f32x4){0.f, 0.f, 0.f, 0.f};

  for (int k0 = 0; k0 < 512; k0 += 64) {
    const int kb = k0 >> 3;
#pragma unroll
    for (int rd = 0; rd < 2; ++rd) {             // A: 512 chunks
      int c = rd * 256 + tid;
      int kg = c >> 6, m = c & 63;
      gload16(Hh + ((size_t)(kb + kg) * NSEQ + row0 + m) * 8,
              As_flat + (size_t)(rd * 256 + wid * 64) * 8);
    }
#pragma unroll
    for (int rd = 0; rd < 8; ++rd) {             // B: 2048 chunks
      int c = rd * 256 + tid;
      int kg = c >> 8, n = c & 255;
      gload16(W2h + ((size_t)(kb + kg) * 256 + n) * 8,
              Bs_flat + (size_t)(rd * 256 + wid * 64) * 8);
    }
    __syncthreads();

#pragma unroll
    for (int ks = 0; ks < 2; ++ks) {
      bf16x8 fa = *(const bf16x8*)&As[ks * 4 + l4][wid * 16 + l15][0];
#pragma unroll
      for (int ni = 0; ni < 16; ++ni) {
        bf16x8 fb = *(const bf16x8*)&Bs[ks * 4 + l4][ni * 16 + l15][0];
        acc[ni] = __builtin_amdgcn_mfma_f32_16x16x32_bf16(fa, fb, acc[ni], 0, 0, 0);
      }
    }
    __syncthreads();
  }

  // ---- step epilogue: rows sidx = row0 + wid*16 + l4*4 + r ----
  const int rowb = row0 + wid * 16 + l4 * 4;
  float x_[4][16];
  float qx[4];
#pragma unroll
  for (int r = 0; r < 4; ++r) {
    qx[r] = QN[rowb + r];
#pragma unroll
    for (int ni = 0; ni < 16; ++ni)
      x_[r][ni] = ZL[(size_t)(rowb + r) * 256 + ni * 16 + l15];
  }

  // v = acc + bias; vn2 per row
  float svv[4] = {0.f, 0.f, 0.f, 0.f};
#pragma unroll
  for (int ni = 0; ni < 16; ++ni) {
    float bv = b2[ni * 16 + l15];
#pragma unroll
    for (int r = 0; r < 4; ++r) {
      float vv = acc[ni][r] + bv;
      acc[ni][r] = vv;
      svv[r] = fmaf(vv, vv, svv[r]);
    }
  }
#pragma unroll
  for (int m = 1; m < 16; m <<= 1)
#pragma unroll
    for (int r = 0; r < 4; ++r) svv[r] += __shfl_xor(svv[r], m);

  float sec_s[4], qsec[4];
#pragma unroll
  for (int r = 0; r < 4; ++r) {
    float vn = sqrtf(fmaxf(svv[r], 1e-14f));
    float arg = vn / qx[r];
    float th = fast_tanh(arg);
    sec_s[r] = th / vn;
    qsec[r] = sech2f(arg);
  }

  // s2p = ||x + sec||^2
  float ssp[4] = {0.f, 0.f, 0.f, 0.f};
#pragma unroll
  for (int ni = 0; ni < 16; ++ni)
#pragma unroll
    for (int r = 0; r < 4; ++r) {
      float s = fmaf(sec_s[r], acc[ni][r], x_[r][ni]);
      ssp[r] = fmaf(s, s, ssp[r]);
    }
#pragma unroll
  for (int m = 1; m < 16; m <<= 1)
#pragma unroll
    for (int r = 0; r < 4; ++r) ssp[r] += __shfl_xor(ssp[r], m);

  float alpha[4], beta[4];
#pragma unroll
  for (int r = 0; r < 4; ++r) {
    float den = fmaxf(ssp[r] + qx[r] * qsec[r], 1e-15f);
    alpha[r] = (ssp[r] + qx[r]) / den;
    beta[r] = qx[r] * sec_s[r] / den;
  }

  // zn = alpha*x + beta*v, overwrite acc; norm
  float snn[4] = {0.f, 0.f, 0.f, 0.f};
#pragma unroll
  for (int ni = 0; ni < 16; ++ni)
#pragma unroll
    for (int r = 0; r < 4; ++r) {
      float zn = fmaf(alpha[r], x_[r][ni], beta[r] * acc[ni][r]);
      acc[ni][r] = zn;
      snn[r] = fmaf(zn, zn, snn[r]);
    }
#pragma unroll
  for (int m = 1; m < 16; m <<= 1)
#pragma unroll
    for (int r = 0; r < 4; ++r) snn[r] += __shfl_xor(snn[r], m);

  float scl[4], qz[4], gs[4];
#pragma unroll
  for (int r = 0; r < 4; ++r) {
    float n = sqrtf(fmaxf(snn[r], 1e-14f));
    bool clip = n > MAXN;
    scl[r] = clip ? MAXN / n : 1.f;
    qz[r] = clip ? QCLIP : (1.f - snn[r]);
    if (clip) gs[r] = GS_CLIP;
    else {
      float opn = 1.f + n;
      gs[r] = 0.34657359f * log2f(opn * opn * __builtin_amdgcn_rcpf(qz[r])) / n;
    }
  }

  // write ZL, QN, Uh(logmap0)
#pragma unroll
  for (int ni = 0; ni < 16; ++ni)
#pragma unroll
    for (int r = 0; r < 4; ++r) {
      float zn = acc[ni][r] * scl[r];
      acc[ni][r] = zn;
      ZL[(size_t)(rowb + r) * 256 + ni * 16 + l15] = zn;
      int d = ni * 16 + l15;
      Uh[((size_t)(d >> 3) * NSEQ + rowb + r) * 8 + (d & 7)] = f2bf(gs[r] * zn);
    }
  if (l15 == 0) {
#pragma unroll
    for (int r = 0; r < 4; ++r) QN[rowb + r] = qz[r];
  }

  if (k < 3) {
    // logmap(x, z_next)
    float sdd[4] = {0.f, 0.f, 0.f, 0.f};
#pragma unroll
    for (int ni = 0; ni < 16; ++ni)
#pragma unroll
      for (int r = 0; r < 4; ++r) {
        float d = acc[ni][r] - x_[r][ni];
        sdd[r] = fmaf(d, d, sdd[r]);
      }
#pragma unroll
    for (int m = 1; m < 16; m <<= 1)
#pragma unroll
      for (int r = 0; r < 4; ++r) sdd[r] += __shfl_xor(sdd[r], m);

    float a2[4], b2c[4];
#pragma unroll
    for (int r = 0; r < 4; ++r) {
      float den2 = fmaxf(sdd[r] + qx[r] * qz[r], 1e-15f);
      a2[r] = (sdd[r] + qx[r]) / den2;
      b2c[r] = qx[r] / den2;
    }
    float sww[4] = {0.f, 0.f, 0.f, 0.f};
#pragma unroll
    for (int ni = 0; ni < 16; ++ni)
#pragma unroll
      for (int r = 0; r < 4; ++r) {
        float wv = b2c[r] * acc[ni][r] - a2[r] * x_[r][ni];
        x_[r][ni] = wv;                           // x no longer needed
        sww[r] = fmaf(wv, wv, sww[r]);
      }
#pragma unroll
    for (int m = 1; m < 16; m <<= 1)
#pragma unroll
      for (int r = 0; r < 4; ++r) sww[r] += __shfl_xor(sww[r], m);

    float vls[4];
#pragma unroll
    for (int r = 0; r < 4; ++r) {
      float wn = sqrtf(fmaxf(sww[r], 1e-14f));
      vls[r] = qx[r] * fast_atanh(fminf(wn, 1.f - 1e-6f)) / wn;
    }

    float p12 = 1.f;
#pragma unroll
    for (int i = 0; i < 12; ++i) p12 *= 0.9f;
    float wsum = (1.f - p12 * 0.9f) / 0.1f;
    float w0 = p12 / wsum;
    float w12 = 1.f / wsum;
#pragma unroll
    for (int ni = 0; ni < 16; ++ni)
#pragma unroll
      for (int r = 0; r < 4; ++r) {
        int dd = 256 + ni * 16 + l15;
        size_t o = ((size_t)(dd >> 3) * NSEQ + rowb + r) * 8 + (dd & 7);
        float velold = bf2f(Uh[o]) + bf2f(Ul[o]);
        float vdrop = bf2f(VOk[(size_t)(rowb + r) * 256 + ni * 16 + l15]);
        float velnew = 0.9f * (velold - w0 * vdrop) + w12 * (vls[r] * x_[r][ni]);
        unsigned short vh = f2bf(velnew);
        Uh[o] = vh;
        Ul[o] = f2bf(velnew - bf2f(vh));
      }
  }
}

// ---------------- GEMM4 (MFMA): r = R1(20480x512 tiled) @ Wr2(512x24->32, single plane) + br2 ----------------
__global__ __launch_bounds__(256) void gemm4_mfma(
    const unsigned short* __restrict__ Ah,
    const unsigned short* __restrict__ Bh,
    const float* __restrict__ br2, float* __restrict__ out, int step)
{
  __shared__ unsigned short As[4][128][8];       // chunk c = kg*128 + m (512 chunks)
  __shared__ unsigned short Bs[4][32][8];        // chunk c = kg*32 + n (128 chunks)
  const int tid = threadIdx.x, lane = tid & 63, wid = tid >> 6;
  const int l15 = lane & 15, l4 = lane >> 4;
  const int row0 = blockIdx.x * 128;
  unsigned short* As_flat = &As[0][0][0];
  unsigned short* Bs_flat = &Bs[0][0][0];

  f32x4 acc[2][2];
#pragma unroll
  for (int i = 0; i < 2; ++i)
#pragma unroll
    for (int j = 0; j < 2; ++j) acc[i][j] = (f32x4){0.f, 0.f, 0.f, 0.f};

  for (int k0 = 0; k0 < 512; k0 += 32) {
    const int kb = k0 >> 3;
#pragma unroll
    for (int rd = 0; rd < 2; ++rd) {
      int c = rd * 256 + tid;
      int kg = c >> 7, m = c & 127;
      gload16(Ah + ((size_t)(kb + kg) * NSEQ + row0 + m) * 8,
              As_flat + (size_t)(rd * 256 + wid * 64) * 8);
    }
    if (tid < 128) {                            // waves 0,1: 128 chunks, lane-linear
      int kg = tid >> 5, n = tid & 31;
      gload16(Bh + ((size_t)(kb + kg) * 32 + n) * 8,
              Bs_flat + (size_t)(wid * 64) * 8);
    }
    __syncthreads();

    bf16x8 fah[2], fbh[2];
#pragma unroll
    for (int mi = 0; mi < 2; ++mi)
      fah[mi] = *(const bf16x8*)&As[l4][wid * 32 + mi * 16 + l15][0];
#pragma unroll
    for (int ni = 0; ni < 2; ++ni)
      fbh[ni] = *(const bf16x8*)&Bs[l4][ni * 16 + l15][0];
#pragma unroll
    for (int mi = 0; mi < 2; ++mi)
#pragma unroll
      for (int ni = 0; ni < 2; ++ni)
        acc[mi][ni] = __builtin_amdgcn_mfma_f32_16x16x32_bf16(fah[mi], fbh[ni], acc[mi][ni], 0, 0, 0);
    __syncthreads();
  }

#pragma unroll
  for (int mi = 0; mi < 2; ++mi)
#pragma unroll
    for (int ni = 0; ni < 2; ++ni) {
      int j = ni * 16 + l15;
      if (j < 24) {
        float bv = br2[j];
#pragma unroll
        for (int r = 0; r < 4; ++r) {
          int row = row0 + wid * 32 + mi * 16 + l4 * 4 + r;
          int c = row >> 12, bf = row & 4095, b = bf >> 6, f = bf & 63;
          size_t base = (((size_t)(c * 64 + b) * 96) + (size_t)step * 24 + j) * 64 + f;
          out[base] = acc[mi][ni][r] + bv;
        }
      }
    }
}

extern "C" void kernel_launch(void* const* d_in, const int* in_sizes, int n_in,
                              void* d_out, int out_size, void* d_ws, size_t ws_size,
                              hipStream_t stream)
{
  const float* trend  = (const float*)d_in[0];
  const float* coarse = (const float*)d_in[1];
  const float* fine   = (const float*)d_in[2];
  const float* resid  = (const float*)d_in[3];
  const float* W_emb  = (const float*)d_in[4];
  const float* b_emb  = (const float*)d_in[5];
  const float* W1  = (const float*)d_in[6];
  const float* b1  = (const float*)d_in[7];
  const float* W2  = (const float*)d_in[8];
  const float* b2  = (const float*)d_in[9];
  const float* Wr1 = (const float*)d_in[10];
  const float* br1 = (const float*)d_in[11];
  const float* Wr2 = (const float*)d_in[12];
  const float* br2 = (const float*)d_in[13];
  float* out = (float*)d_out;

  char* p = (char*)d_ws;
  size_t off = 0;
  auto alloc = [&](size_t bytes) -> void* {
    void* r = p + off;
    off = (off + bytes + 255) & ~(size_t)255;
    return r;
  };
  unsigned short* Uh = (unsigned short*)alloc((size_t)NSEQ * 512 * 2);
  unsigned short* Ul = (unsigned short*)alloc((size_t)NSEQ * 512 * 2);
  unsigned short* Hh = (unsigned short*)alloc((size_t)NSEQ * 512 * 2);
  float* ZL  = (float*)alloc((size_t)NSEQ * 256 * 4);
  float* QN  = (float*)alloc((size_t)NSEQ * 4);
  unsigned short* VO = (unsigned short*)alloc((size_t)3 * NSEQ * 256 * 2);
  float* XT  = (float*)alloc((size_t)5 * 4096 * 336 * 4);
  unsigned short* W1h = (unsigned short*)alloc((size_t)512 * 512 * 2);
  unsigned short* W2h = (unsigned short*)alloc((size_t)512 * 256 * 2);
  unsigned short* Wr1h = (unsigned short*)alloc((size_t)256 * 512 * 2);
  unsigned short* Wr2h = (unsigned short*)alloc((size_t)512 * 32 * 2);
  unsigned short* WgH = (unsigned short*)alloc((size_t)16 * 64 * 8 * 2);
  unsigned short* WgL = (unsigned short*)alloc((size_t)16 * 64 * 8 * 2);

  fold_transpose<<<dim3(64, 6), 256, 0, stream>>>(trend, coarse, fine, resid, XT);
  conv_weight<<<(512 * 512 + 255) / 256, 256, 0, stream>>>(W1, W1h, nullptr, 512, 512, 512);
  conv_weight<<<(512 * 256 + 255) / 256, 256, 0, stream>>>(W2, W2h, nullptr, 512, 256, 256);
  conv_weight<<<(256 * 512 + 255) / 256, 256, 0, stream>>>(Wr1, Wr1h, nullptr, 256, 512, 512);
  conv_weight<<<(512 * 32 + 255) / 256, 256, 0, stream>>>(Wr2, Wr2h, nullptr, 512, 32, 24);
  conv_wemb<<<32, 256, 0, stream>>>(W_emb, WgH, WgL);
  init_kernel<<<NSEQ / 4, 256, 0, stream>>>(XT, WgH, WgL, b_emb, Uh, Ul, ZL, QN, VO);

  for (int k = 0; k < 4; ++k) {
    // H = tanh(U @ W1 + b1)   (20480x512)@(512x512), BK=64
    gemm_bf16<1><<<dim3(160, 4), 256, 0, stream>>>(Uh, 512, W1h, 512, b1, Hh);
    // fused: V = H @ W2 + b2 (in-register) -> hyperbolic step -> ZL/QN/Uh/Ul
    const unsigned short* vok = VO + (size_t)(k < 3 ? k : 0) * NSEQ * 256;
    gemm2_step<<<NSEQ / 64, 256, 0, stream>>>(Hh, W2h, b2, Uh, Ul, ZL, QN, vok, k);
    // R1 = relu(U[:,0:256] @ Wr1 + br1)  (20480x256)@(256x512), BK=64
    gemm_bf16<2><<<dim3(160, 4), 256, 0, stream>>>(Uh, 256, Wr1h, 512, br1, Hh);
    // out slice = R1 @ Wr2 + br2
    gemm4_mfma<<<160, 256, 0, stream>>>(Hh, Wr2h, br2, out, k);
  }
}

// Round 16
// 507.553 us; speedup vs baseline: 1.1840x; 1.1840x over previous
//
#include <hip/hip_runtime.h>
#include <cstddef>

#define NSEQ 20480
#define EPSf 1e-7f
#define MAXN 0.99999f
#define MAXN2 (0.99999f * 0.99999f)
#define QCLIP (1.f - MAXN2)        // 1 - ||z||^2 at the projection boundary
#define GS_CLIP 6.1030949f         // atanh(MAXN)/MAXN

typedef __attribute__((ext_vector_type(8))) short bf16x8;
typedef __attribute__((ext_vector_type(4))) float f32x4;

__device__ __forceinline__ unsigned short f2bf(float x) {
  unsigned u = __float_as_uint(x);
  u += 0x7FFF + ((u >> 16) & 1);
  return (unsigned short)(u >> 16);
}
__device__ __forceinline__ float bf2f(unsigned short h) {
  return __uint_as_float(((unsigned)h) << 16);
}
// async global->LDS, 16B/lane; dst wave-uniform base (HW adds lane*16), src per-lane
__device__ __forceinline__ void gload16(const void* g, void* l) {
  __builtin_amdgcn_global_load_lds(
      (const __attribute__((address_space(1))) void*)g,
      (__attribute__((address_space(3))) void*)l, 16, 0, 0);
}
// hardware-transcendental fast math (v_exp_f32 / v_log_f32 / v_rcp_f32)
__device__ __forceinline__ float fast_exp(float a) {          // e^a
  return exp2f(a * 1.44269504f);
}
__device__ __forceinline__ float fast_tanh(float a) {         // exact formula, HW exp
  float e = fast_exp(2.f * a);
  return 1.f - 2.f * __builtin_amdgcn_rcpf(e + 1.f);
}
__device__ __forceinline__ float fast_atanh(float x) {        // x in [0, 1-1e-6]
  return 0.34657359f * log2f((1.f + x) * __builtin_amdgcn_rcpf(1.f - x));
}
__device__ __forceinline__ float sech2f(float a) {            // 1 - tanh^2(a), a >= 0
  float u = fast_exp(-2.f * a);
  float om = 1.f + u;
  return 4.f * u * __builtin_amdgcn_rcpf(om * om);
}

// Activation tiled layout (same as weights): act[kg][m][e], kg=k>>3, e=k&7
// addr = (kg*NSEQ + m)*8 + e

// ---------------- fold transpose: X[b][l][f] (4 arrays) -> XT[ch][b*64+f][l], ch0 = sum ----------------
__global__ __launch_bounds__(256) void fold_transpose(
    const float* __restrict__ t, const float* __restrict__ c,
    const float* __restrict__ f, const float* __restrict__ r,
    float* __restrict__ XT)
{
  __shared__ float tile[4][56][65];
  const int b = blockIdx.x, l0 = blockIdx.y * 56;
  const int tid = threadIdx.x;
  const int fi = tid & 63, lr0 = tid >> 6;
#pragma unroll
  for (int i = 0; i < 14; ++i) {
    int lr = lr0 + i * 4;
    size_t idx = ((size_t)b * 336 + l0 + lr) * 64 + fi;
    tile[0][lr][fi] = t[idx];
    tile[1][lr][fi] = c[idx];
    tile[2][lr][fi] = f[idx];
    tile[3][lr][fi] = r[idx];
  }
  __syncthreads();
#pragma unroll
  for (int ch = 0; ch < 5; ++ch) {
    for (int i = 0; i < 14; ++i) {
      int idx2 = i * 256 + tid;
      int ff = idx2 / 56, ll = idx2 % 56;
      float v;
      if (ch == 0) v = tile[0][ll][ff] + tile[1][ll][ff] + tile[2][ll][ff] + tile[3][ll][ff];
      else v = tile[ch - 1][ll][ff];
      XT[((size_t)ch * 4096 + (b << 6) + ff) * 336 + l0 + ll] = v;
    }
  }
}

// ---------------- weight split+tile: W[k][n] f32 -> Wh(/Wl) bf16 at [(k>>3)*N + n]*8 + (k&7) ----------------
__global__ __launch_bounds__(256) void conv_weight(
    const float* __restrict__ W, unsigned short* __restrict__ Wh, unsigned short* __restrict__ Wl,
    int K, int N, int Nsrc)
{
  int idx = blockIdx.x * 256 + threadIdx.x;
  if (idx >= K * N) return;
  int k = idx / N, n = idx % N;
  float x = (n < Nsrc) ? W[(size_t)k * Nsrc + n] : 0.f;
  unsigned short h = f2bf(x);
  size_t o = ((size_t)(k >> 3) * N + n) * 8 + (k & 7);
  Wh[o] = h;
  if (Wl) Wl[o] = f2bf(x - bf2f(h));
}

// ---------------- W_emb -> MFMA B-fragment layout: Wg[T][lane][j], k=8*(lane>>4)+j, n=T*16+(lane&15) ----------------
__global__ __launch_bounds__(256) void conv_wemb(
    const float* __restrict__ W_emb, unsigned short* __restrict__ WgH, unsigned short* __restrict__ WgL)
{
  int idx = blockIdx.x * 256 + threadIdx.x;
  if (idx >= 16 * 64 * 8) return;
  int j = idx & 7, ln = (idx >> 3) & 63, T = idx >> 9;
  int k = 8 * (ln >> 4) + j, n = T * 16 + (ln & 15);
  float x = (k < 24) ? W_emb[(size_t)k * 256 + n] : 0.f;
  unsigned short h = f2bf(x);
  WgH[idx] = h;
  WgL[idx] = f2bf(x - bf2f(h));
}

// ---------------- init: MFMA embed + expmap0 + parallel velocity pairs, one WAVE per sequence ----------------
// Zero-LDS, zero-barrier: A-frags direct from XT, B-frags direct from L2-resident WgH/WgL
__global__ __launch_bounds__(256) void init_kernel(
    const float* __restrict__ XT,
    const unsigned short* __restrict__ WgH, const unsigned short* __restrict__ WgL,
    const float* __restrict__ b_emb,
    unsigned short* __restrict__ Uh, unsigned short* __restrict__ Ul,
    float* __restrict__ ZL, float* __restrict__ QN, unsigned short* __restrict__ VO)
{
  const int tid = threadIdx.x, w = tid >> 6, lane = tid & 63;
  const int l15 = lane & 15, l4 = lane >> 4;
  const int sidx = blockIdx.x * 4 + w;

  // A fragment: A[row=l15][k=8*l4+j] = XT[sidx*336 + l15*24 + l4*8 + j]; l4==3 -> 0
  bf16x8 ah, al;
  if (l4 < 3) {
    const float* sp = XT + (size_t)sidx * 336 + l15 * 24 + l4 * 8;  // 16B aligned
    float4 q0 = *(const float4*)sp;
    float4 q1 = *(const float4*)(sp + 4);
    float vv[8] = {q0.x, q0.y, q0.z, q0.w, q1.x, q1.y, q1.z, q1.w};
#pragma unroll
    for (int j = 0; j < 8; ++j) {
      unsigned short h = f2bf(vv[j]);
      ah[j] = (short)h;
      al[j] = (short)f2bf(vv[j] - bf2f(h));
    }
  } else {
#pragma unroll
    for (int j = 0; j < 8; ++j) { ah[j] = 0; al[j] = 0; }
  }

  // 16 N-tiles x 3 split MFMAs, B-frags straight from global (32 KB, L2-resident)
  const bf16x8* BH = (const bf16x8*)WgH;   // index T*64 + lane
  const bf16x8* BL = (const bf16x8*)WgL;
  f32x4 acc[16];
#pragma unroll
  for (int T = 0; T < 16; ++T) acc[T] = (f32x4){0.f, 0.f, 0.f, 0.f};
#pragma unroll
  for (int T = 0; T < 16; ++T) {
    bf16x8 bh = BH[T * 64 + lane];
    bf16x8 bl = BL[T * 64 + lane];
    acc[T] = __builtin_amdgcn_mfma_f32_16x16x32_bf16(ah, bh, acc[T], 0, 0, 0);
    acc[T] = __builtin_amdgcn_mfma_f32_16x16x32_bf16(ah, bl, acc[T], 0, 0, 0);
    acc[T] = __builtin_amdgcn_mfma_f32_16x16x32_bf16(al, bh, acc[T], 0, 0, 0);
  }

  float z_[4][16];
  float q_[4];      // 1 - ||z_s||^2, cancellation-free
  float tn_[4];     // ||z_s|| post-projection
  float vn_[4];     // pre-tanh norm (atanh identity)
  float ls[4] = {0.f, 0.f, 0.f, 0.f};
#pragma unroll
  for (int T = 0; T < 16; ++T) {
    float b = b_emb[T * 16 + l15];
#pragma unroll
    for (int r = 0; r < 4; ++r) {
      float e = fast_tanh(acc[T][r] + b);
      z_[r][T] = e;
      ls[r] = fmaf(e, e, ls[r]);
    }
  }
#pragma unroll
  for (int m = 1; m < 16; m <<= 1)
#pragma unroll
    for (int r = 0; r < 4; ++r) ls[r] += __shfl_xor(ls[r], m);
#pragma unroll
  for (int r = 0; r < 4; ++r) {
    float vn = sqrtf(fmaxf(ls[r], 1e-14f));
    float tt = fast_tanh(vn);           // ||expmap0 pre|| == tanh(||e||) exactly
    bool clip = tt > MAXN;
    float scale = (clip ? MAXN : tt) / vn;
#pragma unroll
    for (int T = 0; T < 16; ++T) z_[r][T] *= scale;
    tn_[r] = clip ? MAXN : tt;
    vn_[r] = vn;
    q_[r] = clip ? QCLIP : sech2f(vn);  // 1 - tanh^2(vn), no cancellation
  }

  // cross-group boundary data: next group's reg0 (z and q)
  float zsh[16], qsh;
#pragma unroll
  for (int T = 0; T < 16; ++T) zsh[T] = __shfl(z_[0][T], (lane + 16) & 63);
  qsh = __shfl(q_[0], (lane + 16) & 63);

  // velocity pairs: group l4 handles t = 4*l4 + p; groups 0-2: 4 pairs, group 3: 1 pair
  float vel[16];
#pragma unroll
  for (int T = 0; T < 16; ++T) vel[T] = 0.f;
  const float p4c = 0.9f * 0.9f * 0.9f * 0.9f;
  const float p8c = p4c * p4c, p12c = p8c * p4c;
  const float wsum = (1.f - p12c * 0.9f) / 0.1f;
  float wt = ((l4 == 0) ? p12c : (l4 == 1) ? p8c : (l4 == 2) ? p4c : 1.f) / wsum;
  const int npairs = (l4 < 3) ? 4 : 1;
#pragma unroll
  for (int p = 0; p < 4; ++p) {
    if (p < npairs) {
      float sd2 = 0.f;                         // ||y - x||^2
#pragma unroll
      for (int T = 0; T < 16; ++T) {
        float zt1 = (p < 3) ? z_[(p + 1) & 3][T] : zsh[T];
        float d = zt1 - z_[p][T];
        sd2 = fmaf(d, d, sd2);
      }
#pragma unroll
      for (int m = 1; m < 16; m <<= 1) sd2 += __shfl_xor(sd2, m);
      float qx = q_[p];
      float qy = (p < 3) ? q_[(p + 1) & 3] : qsh;
      float den = fmaxf(sd2 + qx * qy, 1e-15f);     // 1-2xy+x2y2
      float a2 = (sd2 + qx) / den;                  // (1-2xy+y2)/den
      float b2c = qx / den;                         // (1-x2)/den
      float wd[16];
      float sww = 0.f;
#pragma unroll
      for (int T = 0; T < 16; ++T) {
        float zt1 = (p < 3) ? z_[(p + 1) & 3][T] : zsh[T];
        wd[T] = b2c * zt1 - a2 * z_[p][T];
        sww = fmaf(wd[T], wd[T], sww);
      }
#pragma unroll
      for (int m = 1; m < 16; m <<= 1) sww += __shfl_xor(sww, m);
      float wn = sqrtf(fmaxf(sww, 1e-14f));
      float vls = qx * fast_atanh(fminf(wn, 1.f - 1e-6f)) / wn;   // (2/lam)*atanh/wn
#pragma unroll
      for (int T = 0; T < 16; ++T) {
        float vl = vls * wd[T];
        vel[T] = fmaf(wt, vl, vel[T]);
        if (l4 == 0 && p < 3)
          VO[((size_t)p * NSEQ + sidx) * 256 + T * 16 + l15] = f2bf(vl);
      }
      wt *= (1.f / 0.9f);
    }
  }

#pragma unroll
  for (int T = 0; T < 16; ++T) {
    vel[T] += __shfl_xor(vel[T], 16);
    vel[T] += __shfl_xor(vel[T], 32);
  }

  // outputs in tiled layout: U[kg][m][e]; z13 = group3 reg1
  if (l4 == 3) {
    // atanh(tanh(vn)) == vn: gs = vn/tn (unclipped), const when clipped
    float gs = (tn_[1] >= MAXN) ? GS_CLIP : vn_[1] / tn_[1];
#pragma unroll
    for (int T = 0; T < 16; ++T) {
      int cidx = T * 16 + l15;
      float g = gs * z_[1][T];
      size_t o = ((size_t)(cidx >> 3) * NSEQ + sidx) * 8 + (cidx & 7);
      Uh[o] = f2bf(g);                 // Ul[0:256] never read -> not written
      ZL[(size_t)sidx * 256 + cidx] = z_[1][T];
    }
    if (l15 == 0) QN[sidx] = q_[1];
  }
  if (l4 == 0) {
#pragma unroll
    for (int T = 0; T < 16; ++T) {
      int cidx = 256 + T * 16 + l15;
      unsigned short vh = f2bf(vel[T]);
      size_t o = ((size_t)(cidx >> 3) * NSEQ + sidx) * 8 + (cidx & 7);
      Uh[o] = vh;
      Ul[o] = f2bf(vel[T] - bf2f(vh));
    }
  }
}

// ---------------- single-plane bf16 MFMA GEMM: 128x128 tile, BK=64, global_load_lds staging ----------------
// A: tiled [K/8][NSEQ][8]. B: tiled [K/8][N][8]. K multiple of 64.
// EPI: 0 -> f32 out Cf (row-major ldc); 1 -> tanh; 2 -> relu (tiled bf16 out, hi plane)
template <int EPI>
__global__ __launch_bounds__(256) void gemm_bf16(
    const unsigned short* __restrict__ Ah, int K,
    const unsigned short* __restrict__ Bh, int N,
    const float* __restrict__ bias,
    float* __restrict__ Cf, unsigned short* __restrict__ Ch, int ldc)
{
  __shared__ unsigned short As[8][128][8];       // chunk c = kg*128 + m (1024 chunks)
  __shared__ unsigned short Bs[8][128][8];       // chunk c = kg*128 + n
  const int tid = threadIdx.x;
  const int lane = tid & 63, wid = tid >> 6;
  const int wr = wid >> 1, wc = wid & 1;
  const int l15 = lane & 15, l4 = lane >> 4;
  const int row0 = blockIdx.x * 128, col0 = blockIdx.y * 128;
  unsigned short* As_flat = &As[0][0][0];
  unsigned short* Bs_flat = &Bs[0][0][0];

  f32x4 acc[4][4];
#pragma unroll
  for (int i = 0; i < 4; ++i)
#pragma unroll
    for (int j = 0; j < 4; ++j) acc[i][j] = (f32x4){0.f, 0.f, 0.f, 0.f};

  for (int k0 = 0; k0 < K; k0 += 64) {
    const int kb = k0 >> 3;
#pragma unroll
    for (int rd = 0; rd < 4; ++rd) {
      int c = rd * 256 + tid;                    // lanes -> consecutive m, contiguous 1KB/wave
      int kg = c >> 7, m = c & 127;
      gload16(Ah + ((size_t)(kb + kg) * NSEQ + row0 + m) * 8,
              As_flat + (size_t)(rd * 256 + wid * 64) * 8);
    }
#pragma unroll
    for (int rd = 0; rd < 4; ++rd) {
      int c = rd * 256 + tid;
      int kg = c >> 7, n = c & 127;
      gload16(Bh + ((size_t)(kb + kg) * N + col0 + n) * 8,
              Bs_flat + (size_t)(rd * 256 + wid * 64) * 8);
    }
    __syncthreads();

#pragma unroll
    for (int ks = 0; ks < 2; ++ks) {
      bf16x8 fah[4], fbh[4];
#pragma unroll
      for (int mi = 0; mi < 4; ++mi)
        fah[mi] = *(const bf16x8*)&As[ks * 4 + l4][wr * 64 + mi * 16 + l15][0];
#pragma unroll
      for (int ni = 0; ni < 4; ++ni)
        fbh[ni] = *(const bf16x8*)&Bs[ks * 4 + l4][wc * 64 + ni * 16 + l15][0];
#pragma unroll
      for (int mi = 0; mi < 4; ++mi)
#pragma unroll
        for (int ni = 0; ni < 4; ++ni)
          acc[mi][ni] = __builtin_amdgcn_mfma_f32_16x16x32_bf16(fah[mi], fbh[ni], acc[mi][ni], 0, 0, 0);
    }
    __syncthreads();
  }

#pragma unroll
  for (int mi = 0; mi < 4; ++mi)
#pragma unroll
    for (int ni = 0; ni < 4; ++ni) {
      int cc = col0 + wc * 64 + ni * 16 + l15;
      float bv = bias[cc];
      int rbase = row0 + wr * 64 + mi * 16 + l4 * 4;
#pragma unroll
      for (int r = 0; r < 4; ++r) {
        float v = acc[mi][ni][r] + bv;
        if (EPI == 1) v = tanhf(v);
        else if (EPI == 2) v = fmaxf(v, 0.f);
        if (EPI == 0) {
          Cf[(size_t)(rbase + r) * ldc + cc] = v;
        } else {
          size_t o = ((size_t)(cc >> 3) * NSEQ + rbase + r) * 8 + (cc & 7);
          Ch[o] = f2bf(v);
        }
      }
    }
}

// ---------------- per-sequence step (one WAVE per sequence), all-f32 well-conditioned ----------------
__device__ __forceinline__ float wave_sum_f(float v) {
#pragma unroll
  for (int off = 32; off > 0; off >>= 1) v += __shfl_xor(v, off);
  return v;
}

__global__ __launch_bounds__(256) void step_kernel(
    const float* __restrict__ V, unsigned short* __restrict__ Uh, unsigned short* __restrict__ Ul,
    float* __restrict__ ZL, float* __restrict__ QN, const unsigned short* __restrict__ VOk, int k)
{
  const int tid = threadIdx.x, w = tid >> 6, lane = tid & 63;
  const int sidx = blockIdx.x * 4 + w;

  float x[4], v[4];
#pragma unroll
  for (int j = 0; j < 4; ++j) {
    x[j] = ZL[(size_t)sidx * 256 + lane + 64 * j];
    v[j] = V[(size_t)sidx * 256 + lane + 64 * j];
  }
  float qx = QN[sidx];                         // 1 - ||x||^2, precise

  float svv = 0.f;
#pragma unroll
  for (int j = 0; j < 4; ++j) svv = fmaf(v[j], v[j], svv);
  float vn2 = wave_sum_f(svv);
  float vn = sqrtf(fmaxf(vn2, 1e-14f));
  float arg = vn / qx;                         // lam*vn/2
  float th = fast_tanh(arg);
  float sec_s = th / vn;                       // sec = sec_s * v
  float qsec = sech2f(arg);                    // 1 - th^2

  // s2p = ||x + sec||^2  ->  1+2xy+y2 = s2p + qx ; den = s2p + qx*qsec
  float ssp = 0.f;
#pragma unroll
  for (int j = 0; j < 4; ++j) {
    float s = fmaf(sec_s, v[j], x[j]);
    ssp = fmaf(s, s, ssp);
  }
  float s2p = wave_sum_f(ssp);
  float den = fmaxf(s2p + qx * qsec, 1e-15f);
  float alpha = (s2p + qx) / den;
  float beta = qx * sec_s / den;

  float zn[4];
  float snn = 0.f;
#pragma unroll
  for (int j = 0; j < 4; ++j) {
    zn[j] = alpha * x[j] + beta * v[j];
    snn = fmaf(zn[j], zn[j], snn);
  }
  float n2 = wave_sum_f(snn);
  float n = sqrtf(fmaxf(n2, 1e-14f));
  bool clip = n > MAXN;
  float scl = clip ? MAXN / n : 1.f;
  float qz = clip ? QCLIP : (1.f - n2);
#pragma unroll
  for (int j = 0; j < 4; ++j) {
    zn[j] *= scl;
    ZL[(size_t)sidx * 256 + lane + 64 * j] = zn[j];
  }
  if (lane == 0) QN[sidx] = qz;

  // atanh(n)/n via cancellation-free qz: atanh(n) = 0.5*ln((1+n)^2/qz)
  float gs;
  if (clip) gs = GS_CLIP;
  else {
    float opn = 1.f + n;
    gs = 0.34657359f * log2f(opn * opn * __builtin_amdgcn_rcpf(qz)) / n;
  }
#pragma unroll
  for (int j = 0; j < 4; ++j) {
    int d = lane + 64 * j;
    float g = gs * zn[j];
    size_t o = ((size_t)(d >> 3) * NSEQ + sidx) * 8 + (d & 7);
    Uh[o] = f2bf(g);                 // Ul[0:256] never read -> not written
  }

  if (k < 3) {
    // logmap(x, z_next): sd2b = ||z_next - x||^2
    float sdd = 0.f;
#pragma unroll
    for (int j = 0; j < 4; ++j) {
      float d = zn[j] - x[j];
      sdd = fmaf(d, d, sdd);
    }
    float sd2b = wave_sum_f(sdd);
    float den2 = fmaxf(sd2b + qx * qz, 1e-15f);
    float a2 = (sd2b + qx) / den2;
    float b2 = qx / den2;
    float wv[4];
    float sww = 0.f;
#pragma unroll
    for (int j = 0; j < 4; ++j) {
      wv[j] = b2 * zn[j] - a2 * x[j];
      sww = fmaf(wv[j], wv[j], sww);
    }
    float wn2 = wave_sum_f(sww);
    float wn = sqrtf(fmaxf(wn2, 1e-14f));
    float vls = qx * fast_atanh(fminf(wn, 1.f - 1e-6f)) / wn;

    float p12 = 1.f;
#pragma unroll
    for (int i = 0; i < 12; ++i) p12 *= 0.9f;
    float wsum = (1.f - p12 * 0.9f) / 0.1f;
    float w0 = p12 / wsum;
    float w12 = 1.f / wsum;
#pragma unroll
    for (int j = 0; j < 4; ++j) {
      int dd = 256 + lane + 64 * j;
      size_t o = ((size_t)(dd >> 3) * NSEQ + sidx) * 8 + (dd & 7);
      float velold = bf2f(Uh[o]) + bf2f(Ul[o]);
      float vdrop = bf2f(VOk[(size_t)sidx * 256 + lane + 64 * j]);
      float velnew = 0.9f * (velold - w0 * vdrop) + w12 * (vls * wv[j]);
      unsigned short vh = f2bf(velnew);
      Uh[o] = vh;
      Ul[o] = f2bf(velnew - bf2f(vh));
    }
  }
}

// ---------------- GEMM4 (MFMA): r = R1(20480x512 tiled, single plane) @ Wr2(512x24->32 split) + br2 ----------------
__global__ __launch_bounds__(256) void gemm4_mfma(
    const unsigned short* __restrict__ Ah,
    const unsigned short* __restrict__ Bh, const unsigned short* __restrict__ Bl,
    const float* __restrict__ br2, float* __restrict__ out, int step)
{
  __shared__ unsigned short As[4][128][8];       // chunk c = kg*128 + m (512 chunks)
  __shared__ unsigned short Bs[2][4][32][8];     // chunk c = plane*128 + kg*32 + n
  const int tid = threadIdx.x, lane = tid & 63, wid = tid >> 6;
  const int l15 = lane & 15, l4 = lane >> 4;
  const int row0 = blockIdx.x * 128;
  unsigned short* As_flat = &As[0][0][0];
  unsigned short* Bs_flat = &Bs[0][0][0][0];

  f32x4 acc[2][2];
#pragma unroll
  for (int i = 0; i < 2; ++i)
#pragma unroll
    for (int j = 0; j < 2; ++j) acc[i][j] = (f32x4){0.f, 0.f, 0.f, 0.f};

  for (int k0 = 0; k0 < 512; k0 += 32) {
    const int kb = k0 >> 3;
#pragma unroll
    for (int rd = 0; rd < 2; ++rd) {
      int c = rd * 256 + tid;
      int kg = c >> 7, m = c & 127;
      gload16(Ah + ((size_t)(kb + kg) * NSEQ + row0 + m) * 8,
              As_flat + (size_t)(rd * 256 + wid * 64) * 8);
    }
    {
      int c = tid;                                // 256 chunks, 1 round; lanes contiguous
      int plane = c >> 7, rem = c & 127;
      int kg = rem >> 5, n = rem & 31;
      const unsigned short* srcp = (plane ? Bl : Bh) + ((size_t)(kb + kg) * 32 + n) * 8;
      gload16(srcp, Bs_flat + (size_t)(wid * 64) * 8);
    }
    __syncthreads();

    bf16x8 fah[2], fbh[2], fbl[2];
#pragma unroll
    for (int mi = 0; mi < 2; ++mi)
      fah[mi] = *(const bf16x8*)&As[l4][wid * 32 + mi * 16 + l15][0];
#pragma unroll
    for (int ni = 0; ni < 2; ++ni) {
      fbh[ni] = *(const bf16x8*)&Bs[0][l4][ni * 16 + l15][0];
      fbl[ni] = *(const bf16x8*)&Bs[1][l4][ni * 16 + l15][0];
    }
#pragma unroll
    for (int mi = 0; mi < 2; ++mi)
#pragma unroll
      for (int ni = 0; ni < 2; ++ni) {
        acc[mi][ni] = __builtin_amdgcn_mfma_f32_16x16x32_bf16(fah[mi], fbh[ni], acc[mi][ni], 0, 0, 0);
        acc[mi][ni] = __builtin_amdgcn_mfma_f32_16x16x32_bf16(fah[mi], fbl[ni], acc[mi][ni], 0, 0, 0);
      }
    __syncthreads();
  }

#pragma unroll
  for (int mi = 0; mi < 2; ++mi)
#pragma unroll
    for (int ni = 0; ni < 2; ++ni) {
      int j = ni * 16 + l15;
      if (j < 24) {
        float bv = br2[j];
#pragma unroll
        for (int r = 0; r < 4; ++r) {
          int row = row0 + wid * 32 + mi * 16 + l4 * 4 + r;
          int c = row >> 12, bf = row & 4095, b = bf >> 6, f = bf & 63;
          size_t base = (((size_t)(c * 64 + b) * 96) + (size_t)step * 24 + j) * 64 + f;
          out[base] = acc[mi][ni][r] + bv;
        }
      }
    }
}

extern "C" void kernel_launch(void* const* d_in, const int* in_sizes, int n_in,
                              void* d_out, int out_size, void* d_ws, size_t ws_size,
                              hipStream_t stream)
{
  const float* trend  = (const float*)d_in[0];
  const float* coarse = (const float*)d_in[1];
  const float* fine   = (const float*)d_in[2];
  const float* resid  = (const float*)d_in[3];
  const float* W_emb  = (const float*)d_in[4];
  const float* b_emb  = (const float*)d_in[5];
  const float* W1  = (const float*)d_in[6];
  const float* b1  = (const float*)d_in[7];
  const float* W2  = (const float*)d_in[8];
  const float* b2  = (const float*)d_in[9];
  const float* Wr1 = (const float*)d_in[10];
  const float* br1 = (const float*)d_in[11];
  const float* Wr2 = (const float*)d_in[12];
  const float* br2 = (const float*)d_in[13];
  float* out = (float*)d_out;

  char* p = (char*)d_ws;
  size_t off = 0;
  auto alloc = [&](size_t bytes) -> void* {
    void* r = p + off;
    off = (off + bytes + 255) & ~(size_t)255;
    return r;
  };
  unsigned short* Uh = (unsigned short*)alloc((size_t)NSEQ * 512 * 2);
  unsigned short* Ul = (unsigned short*)alloc((size_t)NSEQ * 512 * 2);
  unsigned short* Hh = (unsigned short*)alloc((size_t)NSEQ * 512 * 2);
  float* V   = (float*)alloc((size_t)NSEQ * 256 * 4);
  float* ZL  = (float*)alloc((size_t)NSEQ * 256 * 4);
  float* QN  = (float*)alloc((size_t)NSEQ * 4);
  unsigned short* VO = (unsigned short*)alloc((size_t)3 * NSEQ * 256 * 2);
  float* XT  = (float*)alloc((size_t)5 * 4096 * 336 * 4);
  unsigned short* W1h = (unsigned short*)alloc((size_t)512 * 512 * 2);
  unsigned short* W2h = (unsigned short*)alloc((size_t)512 * 256 * 2);
  unsigned short* Wr1h = (unsigned short*)alloc((size_t)256 * 512 * 2);
  unsigned short* Wr2h = (unsigned short*)alloc((size_t)512 * 32 * 2);
  unsigned short* Wr2l = (unsigned short*)alloc((size_t)512 * 32 * 2);
  unsigned short* WgH = (unsigned short*)alloc((size_t)16 * 64 * 8 * 2);
  unsigned short* WgL = (unsigned short*)alloc((size_t)16 * 64 * 8 * 2);

  fold_transpose<<<dim3(64, 6), 256, 0, stream>>>(trend, coarse, fine, resid, XT);
  conv_weight<<<(512 * 512 + 255) / 256, 256, 0, stream>>>(W1, W1h, nullptr, 512, 512, 512);
  conv_weight<<<(512 * 256 + 255) / 256, 256, 0, stream>>>(W2, W2h, nullptr, 512, 256, 256);
  conv_weight<<<(256 * 512 + 255) / 256, 256, 0, stream>>>(Wr1, Wr1h, nullptr, 256, 512, 512);
  conv_weight<<<(512 * 32 + 255) / 256, 256, 0, stream>>>(Wr2, Wr2h, Wr2l, 512, 32, 24);
  conv_wemb<<<32, 256, 0, stream>>>(W_emb, WgH, WgL);
  init_kernel<<<NSEQ / 4, 256, 0, stream>>>(XT, WgH, WgL, b_emb, Uh, Ul, ZL, QN, VO);

  for (int k = 0; k < 4; ++k) {
    // H = tanh(U @ W1 + b1)   (20480x512)@(512x512), BK=64
    gemm_bf16<1><<<dim3(160, 4), 256, 0, stream>>>(Uh, 512, W1h, 512, b1, nullptr, Hh, 512);
    // V = H @ W2 + b2         (20480x512)@(512x256), f32 out, BK=64
    gemm_bf16<0><<<dim3(160, 2), 256, 0, stream>>>(Hh, 512, W2h, 256, b2, V, nullptr, 256);
    const unsigned short* vok = VO + (size_t)(k < 3 ? k : 0) * NSEQ * 256;
    step_kernel<<<NSEQ / 4, 256, 0, stream>>>(V, Uh, Ul, ZL, QN, vok, k);
    // R1 = relu(U[:,0:256] @ Wr1 + br1)  (20480x256)@(256x512), BK=64
    gemm_bf16<2><<<dim3(160, 4), 256, 0, stream>>>(Uh, 256, Wr1h, 512, br1, nullptr, Hh, 512);
    // out slice = R1 @ Wr2 + br2
    gemm4_mfma<<<160, 256, 0, stream>>>(Hh, Wr2h, Wr2l, br2, out, k);
  }
}